// Round 8
// baseline (268.130 us; speedup 1.0000x reference)
//
#include <hip/hip_runtime.h>
#include <math.h>

#define NEARP 0.01f
#define BLUR 0.3f
#define MAX_ALPHA 0.999f
#define QCUT 32.0f     // mahalanobis^2 cutoff: culled alpha <= op*e^-16 ~ 1e-7
#define RT 8           // render tile 8x8, one wave per tile
#define TEXIT 1e-5f    // early-exit transmittance; residual error <= 1e-5

__device__ __forceinline__ float sigmoidf_(float x) {
    return 1.0f / (1.0f + expf(-x));
}

// ---------------------------------------------------------------------------
// Dispatch 1: blocks [0,nPrep) = preprocess ; blocks [nPrep,..) = rank sort.
// The two halves touch disjoint data (sort recomputes tz from means+viewmat),
// so no ordering between them is required.
// payload: f0=(m2x,m2y,iap,ibp) f1=(icp,op,cr,cg) f2=(cb,0,0,0); alpha=op*exp2(quad)
// ---------------------------------------------------------------------------
__global__ void __launch_bounds__(256) gs_prep_sort2(
        const float* __restrict__ viewmats,
        const float* __restrict__ Ks,
        const float* __restrict__ means,
        const float* __restrict__ quats,
        const float* __restrict__ log_scales,
        const float* __restrict__ opac_logits,
        const float* __restrict__ color_logits,
        float4* __restrict__ ubbox,
        float4* __restrict__ upay,
        int* __restrict__ perm,
        int N, int C, int nPrep) {
    if ((int)blockIdx.x < nPrep) {
        // ---------------- preprocess ----------------
        int idx = blockIdx.x * 256 + threadIdx.x;
        if (idx >= N * C) return;
        int c = idx / N;
        int n = idx - c * N;

        float qw = quats[n * 4 + 0], qx = quats[n * 4 + 1];
        float qy = quats[n * 4 + 2], qz = quats[n * 4 + 3];
        float qn = rsqrtf(qw * qw + qx * qx + qy * qy + qz * qz);
        float w = qw * qn, x = qx * qn, y = qy * qn, z = qz * qn;
        float R00 = 1.0f - 2.0f * (y * y + z * z), R01 = 2.0f * (x * y - w * z), R02 = 2.0f * (x * z + w * y);
        float R10 = 2.0f * (x * y + w * z), R11 = 1.0f - 2.0f * (x * x + z * z), R12 = 2.0f * (y * z - w * x);
        float R20 = 2.0f * (x * z - w * y), R21 = 2.0f * (y * z + w * x), R22 = 1.0f - 2.0f * (x * x + y * y);

        float s0 = expf(log_scales[n * 3 + 0]);
        float s1 = expf(log_scales[n * 3 + 1]);
        float s2 = expf(log_scales[n * 3 + 2]);

        float M00 = R00 * s0, M01 = R01 * s1, M02 = R02 * s2;
        float M10 = R10 * s0, M11 = R11 * s1, M12 = R12 * s2;
        float M20 = R20 * s0, M21 = R21 * s1, M22 = R22 * s2;
        float C00 = M00 * M00 + M01 * M01 + M02 * M02;
        float C01 = M00 * M10 + M01 * M11 + M02 * M12;
        float C02 = M00 * M20 + M01 * M21 + M02 * M22;
        float C11 = M10 * M10 + M11 * M11 + M12 * M12;
        float C12 = M10 * M20 + M11 * M21 + M12 * M22;
        float C22 = M20 * M20 + M21 * M21 + M22 * M22;

        const float* vm = viewmats + c * 16;
        float V00 = vm[0], V01 = vm[1], V02 = vm[2], T0 = vm[3];
        float V10 = vm[4], V11 = vm[5], V12 = vm[6], T1 = vm[7];
        float V20 = vm[8], V21 = vm[9], V22 = vm[10], T2 = vm[11];
        float mex = means[n * 3 + 0], mey = means[n * 3 + 1], mez = means[n * 3 + 2];
        float tx = V00 * mex + V01 * mey + V02 * mez + T0;
        float ty = V10 * mex + V11 * mey + V12 * mez + T1;
        float tzv = V20 * mex + V21 * mey + V22 * mez + T2;

        float fx = Ks[c * 9 + 0], fy = Ks[c * 9 + 4], cx = Ks[c * 9 + 2], cy = Ks[c * 9 + 5];
        float tzs = (tzv > NEARP) ? tzv : NEARP;
        float iz = 1.0f / tzs;
        float m2x = fx * tx * iz + cx;
        float m2y = fy * ty * iz + cy;

        float A00 = V00 * C00 + V01 * C01 + V02 * C02;
        float A01 = V00 * C01 + V01 * C11 + V02 * C12;
        float A02 = V00 * C02 + V01 * C12 + V02 * C22;
        float A10 = V10 * C00 + V11 * C01 + V12 * C02;
        float A11 = V10 * C01 + V11 * C11 + V12 * C12;
        float A12 = V10 * C02 + V11 * C12 + V12 * C22;
        float A20 = V20 * C00 + V21 * C01 + V22 * C02;
        float A21 = V20 * C01 + V21 * C11 + V22 * C12;
        float A22 = V20 * C02 + V21 * C12 + V22 * C22;
        float S00 = A00 * V00 + A01 * V01 + A02 * V02;
        float S01 = A00 * V10 + A01 * V11 + A02 * V12;
        float S02 = A00 * V20 + A01 * V21 + A02 * V22;
        float S11 = A10 * V10 + A11 * V11 + A12 * V12;
        float S12 = A10 * V20 + A11 * V21 + A12 * V22;
        float S22 = A20 * V20 + A21 * V21 + A22 * V22;

        float J00 = fx * iz, J02 = -fx * tx * iz * iz;
        float J11 = fy * iz, J12 = -fy * ty * iz * iz;

        float c2_00 = J00 * J00 * S00 + 2.0f * J00 * J02 * S02 + J02 * J02 * S22;
        float c2_01 = J00 * J11 * S01 + J00 * J12 * S02 + J02 * J11 * S12 + J02 * J12 * S22;
        float c2_11 = J11 * J11 * S11 + 2.0f * J11 * J12 * S12 + J12 * J12 * S22;

        float a = c2_00 + BLUR;
        float cc = c2_11 + BLUR;
        float b = c2_01;
        float det = a * cc - b * b;
        bool valid = (tzv > NEARP) && (det > 1e-12f);

        float ia, ib, ic, op, r;
        if (valid) {
            float inv = 1.0f / det;
            ia = cc * inv;
            ib = -b * inv;
            ic = a * inv;
            op = sigmoidf_(opac_logits[n]);
            float lmax = 0.5f * (a + cc) + sqrtf(0.25f * (a - cc) * (a - cc) + b * b);
            r = sqrtf(QCUT * lmax);
        } else {
            ia = 0.0f; ib = 0.0f; ic = 0.0f; op = 0.0f;
            r = -1.0f;   // culled from every tile; exact contribution is 0
        }
        float cr = sigmoidf_(color_logits[n * 3 + 0]);
        float cg = sigmoidf_(color_logits[n * 3 + 1]);
        float cb = sigmoidf_(color_logits[n * 3 + 2]);

        const float KQ = 0.721347520444482f;   // 0.5*log2(e)
        float iap = -KQ * ia;
        float ibp = -2.0f * KQ * ib;
        float icp = -KQ * ic;

        int gi = c * N + n;
        ubbox[gi] = make_float4(m2x, m2y, r, 0.0f);
        upay[(size_t)gi * 3 + 0] = make_float4(m2x, m2y, iap, ibp);
        upay[(size_t)gi * 3 + 1] = make_float4(icp, op, cr, cg);
        upay[(size_t)gi * 3 + 2] = make_float4(cb, 0.0f, 0.0f, 0.0f);
    } else {
        // ---------------- rank sort (tz recomputed; independent of prep) ---
        int swid = ((int)blockIdx.x - nPrep) * 4 + ((int)threadIdx.x >> 6);
        if (swid >= C * N) return;     // wave-uniform
        int lane = threadIdx.x & 63;
        int c = swid / N;
        int i = swid - c * N;
        const float* vm = viewmats + c * 16;
        float V20 = vm[8], V21 = vm[9], V22 = vm[10], T2 = vm[11];
        float ti = V20 * means[i * 3 + 0] + V21 * means[i * 3 + 1] + V22 * means[i * 3 + 2] + T2;
        int rank = 0;
        for (int j = lane; j < N; j += 64) {
            float tj = V20 * means[j * 3 + 0] + V21 * means[j * 3 + 1] + V22 * means[j * 3 + 2] + T2;
            rank += (int)((tj < ti) || (tj == ti && j < i));   // stable
        }
#pragma unroll
        for (int off = 1; off < 64; off <<= 1)
            rank += __shfl_xor(rank, off, 64);
        if (lane == 0) perm[c * N + rank] = i;
    }
}

// ---------------------------------------------------------------------------
// Dispatch 2: render. Block = one 8x8 tile (64 threads = 1 wave, 1 px/lane).
// Pipelined ballot-cull of 16 chunks -> masks in SGPRs; walk survivors in
// ascending rank via shuffle; early-exit when the whole tile is saturated.
// ---------------------------------------------------------------------------
__global__ void __launch_bounds__(64) gs_render8(
        const float4* __restrict__ ubbox,
        const float4* __restrict__ upay,
        const int* __restrict__ perm,
        float* __restrict__ out,
        int N, int W, int H) {
    int c = blockIdx.z;
    float x0 = (float)(blockIdx.x * RT);
    float y0 = (float)(blockIdx.y * RT);
    float x1 = x0 + (float)RT;
    float y1 = y0 + (float)RT;
    int lane = threadIdx.x;
    float px = x0 + (float)(lane & 7) + 0.5f;
    float py = y0 + (float)(lane >> 3) + 0.5f;

    const int* pc = perm + (size_t)c * N;
    const float4* bb = ubbox + (size_t)c * N;
    const float4* pay = upay + (size_t)c * N * 3;

    float T = 1.0f, ar = 0.0f, ag = 0.0f, abv = 0.0f;
    int nchunk = (N + 63) >> 6;
    bool done = false;

    for (int g0 = 0; g0 < nchunk && !done; g0 += 16) {
        int gcnt = min(16, nchunk - g0);
        unsigned long long masks[16];
        int idxv[16];
#pragma unroll
        for (int u = 0; u < 16; u++) {       // compile-time indices (rule #20)
            masks[u] = 0ull;
            idxv[u] = 0;
            if (u < gcnt) {
                int g = (g0 + u) * 64 + lane;
                bool pred = false;
                int id = 0;
                if (g < N) {
                    id = pc[g];              // coalesced
                    float4 b = bb[id];       // scattered, L2-resident
                    pred = (b.z >= 0.0f) &&
                           (b.x - b.z <= x1) && (b.x + b.z >= x0) &&
                           (b.y - b.z <= y1) && (b.y + b.z >= y0);
                }
                idxv[u] = id;
                masks[u] = __ballot(pred);
            }
        }
#pragma unroll
        for (int u = 0; u < 16; u++) {
            if (u < gcnt && !done) {
                unsigned long long m = masks[u];
                for (; m; m &= (m - 1)) {
                    int bit = __ffsll((unsigned long long)m) - 1;   // asc rank
                    int id = __shfl(idxv[u], bit, 64);
                    float4 f0 = pay[(size_t)id * 3 + 0];
                    float4 f1 = pay[(size_t)id * 3 + 1];
                    float4 f2 = pay[(size_t)id * 3 + 2];
                    float dx = px - f0.x;
                    float dy = py - f0.y;
                    float quad = dx * (f0.z * dx + f0.w * dy) + f1.x * dy * dy;  // <= 0
                    float alpha = fminf(f1.y * exp2f(quad), MAX_ALPHA);
                    float wgt = alpha * T;
                    ar += wgt * f1.z;
                    ag += wgt * f1.w;
                    abv += wgt * f2.x;
                    T *= (1.0f - alpha);
                }
                if (__all(T < TEXIT)) done = true;   // residual <= 1e-5
            }
        }
    }

    int x = blockIdx.x * RT + (lane & 7);
    int y = blockIdx.y * RT + (lane >> 3);
    if (x < W && y < H) {
        size_t o = (((size_t)c * H + y) * W + x) * 3;
        out[o + 0] = ar;
        out[o + 1] = ag;
        out[o + 2] = abv;
    }
}

extern "C" void kernel_launch(void* const* d_in, const int* in_sizes, int n_in,
                              void* d_out, int out_size, void* d_ws, size_t ws_size,
                              hipStream_t stream) {
    const float* viewmats = (const float*)d_in[0];
    const float* Ks = (const float*)d_in[1];
    const float* means = (const float*)d_in[2];
    const float* quats = (const float*)d_in[3];
    const float* log_scales = (const float*)d_in[4];
    const float* opac_logits = (const float*)d_in[5];
    const float* color_logits = (const float*)d_in[6];
    float* out = (float*)d_out;

    int N = in_sizes[2] / 3;       // means: (N,3)
    int C = in_sizes[0] / 16;      // viewmats: (C,4,4)
    int pix = out_size / (C * 3);
    int W = (int)(sqrt((double)pix) + 0.5);
    int H = pix / W;

    // workspace: ubbox C*N | upay C*N*3 | perm C*N
    float4* ubbox = (float4*)d_ws;
    float4* upay = ubbox + (size_t)C * N;
    int* perm = (int*)(upay + (size_t)C * N * 3);

    int total = C * N;
    int nPrep = (total + 255) / 256;
    int nSortBlk = (total + 3) / 4;          // 4 sort waves per 256-thr block
    gs_prep_sort2<<<nPrep + nSortBlk, 256, 0, stream>>>(
        viewmats, Ks, means, quats, log_scales, opac_logits, color_logits,
        ubbox, upay, perm, N, C, nPrep);

    dim3 rgrid((W + RT - 1) / RT, (H + RT - 1) / RT, C);
    gs_render8<<<rgrid, 64, 0, stream>>>(ubbox, upay, perm, out, N, W, H);
}